// Round 8
// baseline (769.414 us; speedup 1.0000x reference)
//
#include <hip/hip_runtime.h>
#include <math.h>
#include <stdint.h>

#define D_MODEL 1024
#define NUM_HEADS 16
#define HEAD_SIZE 64
#define SEQ_T 2048

typedef __bf16 bf16;
typedef __bf16 bf16x8 __attribute__((ext_vector_type(8)));
typedef float f32x4 __attribute__((ext_vector_type(4)));

__device__ __forceinline__ void gld_lds16(const bf16* g, bf16* l) {
    __builtin_amdgcn_global_load_lds(
        (__attribute__((address_space(1))) void*)(const_cast<bf16*>(g)),
        (__attribute__((address_space(3))) void*)(l), 16, 0, 0);
}

struct __align__(8) b4pack { bf16 v[4]; };

// ---------------- fused f32 -> bf16 cast of all 4 weight matrices ----------------
__global__ __launch_bounds__(256) void cast_all_weights(const float* __restrict__ s0, bf16* __restrict__ d0, int n0,
                                                        const float* __restrict__ s1, bf16* __restrict__ d1, int n1,
                                                        const float* __restrict__ s2, bf16* __restrict__ d2, int n2,
                                                        const float* __restrict__ s3, bf16* __restrict__ d3, int n3) {
    int i = (blockIdx.x * 256 + threadIdx.x) * 4;
    const float* src;
    bf16* dst;
    if (i < n0) { src = s0; dst = d0; }
    else if (i < n0 + n1) { i -= n0; src = s1; dst = d1; }
    else if (i < n0 + n1 + n2) { i -= n0 + n1; src = s2; dst = d2; }
    else { i -= n0 + n1 + n2; if (i >= n3) return; src = s3; dst = d3; }
    float4 v = *(const float4*)(src + i);
    b4pack o;
    o.v[0] = (bf16)v.x; o.v[1] = (bf16)v.y; o.v[2] = (bf16)v.z; o.v[3] = (bf16)v.w;
    *(b4pack*)(dst + i) = o;
}

// ---------------- fused RMSNorm + RoPE ----------------
__global__ __launch_bounds__(256) void rmsnorm_rope_kernel(const float* __restrict__ x,
                                                           const float* __restrict__ scale,
                                                           bf16* __restrict__ xn,
                                                           bf16* __restrict__ rp, int T) {
    __shared__ float red[4];
    int row = blockIdx.x;
    int t = row % T;
    const float* xp = x + (size_t)row * D_MODEL;
    int tid = threadIdx.x;
    float4 xv = *(const float4*)(xp + tid * 4);
    float s = xv.x * xv.x + xv.y * xv.y + xv.z * xv.z + xv.w * xv.w;
    for (int off = 32; off; off >>= 1) s += __shfl_down(s, off);
    if ((tid & 63) == 0) red[tid >> 6] = s;
    __syncthreads();
    if (tid == 0) red[0] = red[0] + red[1] + red[2] + red[3];
    __syncthreads();
    float inv = rsqrtf(red[0] * (1.0f / D_MODEL) + 1e-6f);
    float4 sc = *(const float4*)(scale + tid * 4);
    float n0 = xv.x * inv * sc.x, n1 = xv.y * inv * sc.y;
    float n2 = xv.z * inv * sc.z, n3 = xv.w * inv * sc.w;
    b4pack pn;
    pn.v[0] = (bf16)n0; pn.v[1] = (bf16)n1; pn.v[2] = (bf16)n2; pn.v[3] = (bf16)n3;
    *(b4pack*)(xn + (size_t)row * D_MODEL + tid * 4) = pn;
    int p0 = 2 * tid;
    float th0 = expf(-0.2878231366242557f * (float)(p0 & 31));        // ln(10000)/32
    float th1 = expf(-0.2878231366242557f * (float)((p0 + 1) & 31));
    float s0, c0, s1, c1;
    sincosf((float)t * th0, &s0, &c0);
    sincosf((float)t * th1, &s1, &c1);
    b4pack pr;
    pr.v[0] = (bf16)(n0 * c0 - n1 * s0);
    pr.v[1] = (bf16)(n1 * c0 + n0 * s0);
    pr.v[2] = (bf16)(n2 * c1 - n3 * s1);
    pr.v[3] = (bf16)(n3 * c1 + n2 * s1);
    *(b4pack*)(rp + (size_t)row * D_MODEL + tid * 4) = pr;
}

// ---------------- RMSNorm only ----------------
__global__ __launch_bounds__(256) void rmsnorm_kernel(const float* __restrict__ x,
                                                      const float* __restrict__ scale,
                                                      bf16* __restrict__ out) {
    __shared__ float red[4];
    int row = blockIdx.x;
    const float* xp = x + (size_t)row * D_MODEL;
    bf16* op = out + (size_t)row * D_MODEL;
    int tid = threadIdx.x;
    float s = 0.f;
    for (int i = tid; i < D_MODEL; i += 256) { float v = xp[i]; s += v * v; }
    for (int off = 32; off; off >>= 1) s += __shfl_down(s, off);
    if ((tid & 63) == 0) red[tid >> 6] = s;
    __syncthreads();
    if (tid == 0) red[0] = red[0] + red[1] + red[2] + red[3];
    __syncthreads();
    float inv = rsqrtf(red[0] * (1.0f / D_MODEL) + 1e-6f);
    for (int i = tid; i < D_MODEL; i += 256) op[i] = (bf16)(xp[i] * inv * scale[i]);
}

// ---------------- bf16 MFMA GEMM, 128x128 tile (m97 structure) ----------------
template <int ACT, int ADD, int OUT_BF16, int VT>
__global__ __launch_bounds__(256) void gemm_bf16(const bf16* __restrict__ A,
                                                 const bf16* __restrict__ A2, int splitN,
                                                 const bf16* __restrict__ W,
                                                 const float* __restrict__ bias,
                                                 float* __restrict__ Cf,
                                                 bf16* __restrict__ Cb,
                                                 bf16* __restrict__ Vtp, int Tlen,
                                                 int M, int N, int K) {
    __shared__ __align__(16) bf16 As[128 * 32];
    __shared__ __align__(16) bf16 Bs[128 * 32];
    int tid = threadIdx.x;
    int m0 = blockIdx.y * 128, n0 = blockIdx.x * 128;
    const bf16* Ag = (n0 < splitN) ? A : A2;

    int lane = tid & 63, w = tid >> 6;
    int wm = w >> 1, wn = w & 1;
    int lm = lane & 15, quad = lane >> 4;

    int c0 = tid, c1 = tid + 256;
    int ar0 = c0 >> 2, ak0 = (c0 & 3) * 8;
    int ar1 = c1 >> 2, ak1 = (c1 & 3) * 8;

    f32x4 acc[4][4];
#pragma unroll
    for (int i = 0; i < 4; i++)
#pragma unroll
        for (int j = 0; j < 4; j++)
#pragma unroll
            for (int r = 0; r < 4; r++) acc[i][j][r] = 0.f;

    int abase = (wm * 64 + lm) * 32 + quad * 8;
    int bbase = (wn * 64 + lm) * 32 + quad * 8;

    for (int k0 = 0; k0 < K; k0 += 32) {
        __syncthreads();
        gld_lds16(Ag + (size_t)(m0 + ar0) * K + k0 + ak0, As + c0 * 8);
        gld_lds16(Ag + (size_t)(m0 + ar1) * K + k0 + ak1, As + c1 * 8);
        gld_lds16(W  + (size_t)(n0 + ar0) * K + k0 + ak0, Bs + c0 * 8);
        gld_lds16(W  + (size_t)(n0 + ar1) * K + k0 + ak1, Bs + c1 * 8);
        __syncthreads();
        bf16x8 af[4], bfr[4];
#pragma unroll
        for (int i = 0; i < 4; i++) af[i] = *(const bf16x8*)&As[abase + i * 16 * 32];
#pragma unroll
        for (int j = 0; j < 4; j++) bfr[j] = *(const bf16x8*)&Bs[bbase + j * 16 * 32];
#pragma unroll
        for (int i = 0; i < 4; i++)
#pragma unroll
            for (int j = 0; j < 4; j++)
                acc[i][j] = __builtin_amdgcn_mfma_f32_16x16x32_bf16(af[i], bfr[j], acc[i][j], 0, 0, 0);
    }

    if (VT && n0 >= 2 * D_MODEL) {
#pragma unroll
        for (int j = 0; j < 4; j++) {
            int col = n0 + wn * 64 + j * 16 + lm;
            int dimg = col - 2 * D_MODEL;
            float bv = bias[col];
#pragma unroll
            for (int i = 0; i < 4; i++) {
                int row0 = m0 + wm * 64 + i * 16 + quad * 4;
                int bb = row0 / Tlen, t0 = row0 % Tlen;
                b4pack pk;
#pragma unroll
                for (int r = 0; r < 4; r++) pk.v[r] = (bf16)(acc[i][j][r] + bv);
                *(b4pack*)(Vtp + ((size_t)bb * D_MODEL + dimg) * Tlen + t0) = pk;
            }
        }
        return;
    }

#pragma unroll
    for (int j = 0; j < 4; j++) {
        int col = n0 + wn * 64 + j * 16 + lm;
        float bv = bias[col];
#pragma unroll
        for (int i = 0; i < 4; i++) {
#pragma unroll
            for (int r = 0; r < 4; r++) {
                int row = m0 + wm * 64 + i * 16 + quad * 4 + r;
                float v = acc[i][j][r] + bv;
                if (ACT == 1) v = v / (1.f + __expf(-v));
                size_t idx = (size_t)row * N + col;
                if (ADD) v += Cf[idx];
                if (OUT_BF16) Cb[idx] = (bf16)v;
                else Cf[idx] = v;
            }
        }
    }
}

// ---------------- skinny bf16 MFMA GEMM, 64x128 tile (for N=1024 GEMMs) -------------
template <int ADD>
__global__ __launch_bounds__(256) void gemm_bf16_skinny(const bf16* __restrict__ A,
                                                        const bf16* __restrict__ W,
                                                        const float* __restrict__ bias,
                                                        float* __restrict__ Cf,
                                                        int M, int N, int K) {
    __shared__ __align__(16) bf16 As[64 * 32];   // 4 KB
    __shared__ __align__(16) bf16 Bs[128 * 32];  // 8 KB
    int tid = threadIdx.x;
    int m0 = blockIdx.y * 64, n0 = blockIdx.x * 128;

    int lane = tid & 63, w = tid >> 6;
    int lm = lane & 15, quad = lane >> 4;

    int ar = tid >> 2, ak = (tid & 3) * 8;         // A: 256 chunks
    int c1 = tid + 256;
    int br1 = c1 >> 2, bk1 = (c1 & 3) * 8;         // B: 512 chunks

    f32x4 acc[8];
#pragma unroll
    for (int j = 0; j < 8; j++)
#pragma unroll
        for (int r = 0; r < 4; r++) acc[j][r] = 0.f;

    int abase = (w * 16 + lm) * 32 + quad * 8;
    int bbase = lm * 32 + quad * 8;

    for (int k0 = 0; k0 < K; k0 += 32) {
        __syncthreads();
        gld_lds16(A + (size_t)(m0 + ar) * K + k0 + ak, As + tid * 8);
        gld_lds16(W + (size_t)(n0 + ar) * K + k0 + ak, Bs + tid * 8);
        gld_lds16(W + (size_t)(n0 + br1) * K + k0 + bk1, Bs + c1 * 8);
        __syncthreads();
        bf16x8 af = *(const bf16x8*)&As[abase];
#pragma unroll
        for (int j = 0; j < 8; j++) {
            bf16x8 bfr = *(const bf16x8*)&Bs[bbase + j * 16 * 32];
            acc[j] = __builtin_amdgcn_mfma_f32_16x16x32_bf16(af, bfr, acc[j], 0, 0, 0);
        }
    }

#pragma unroll
    for (int j = 0; j < 8; j++) {
        int col = n0 + j * 16 + lm;
        float bv = bias[col];
#pragma unroll
        for (int r = 0; r < 4; r++) {
            int row = m0 + w * 16 + quad * 4 + r;
            float v = acc[j][r] + bv;
            size_t idx = (size_t)row * N + col;
            if (ADD) v += Cf[idx];
            Cf[idx] = v;
        }
    }
}

// ---------------- MFMA flash attention: 4-wave blocks, 4-round balanced grid --------
// 1024 blocks (4/CU, 16 waves/CU). bidx = ((r*32 + (bh>>3)*8 + tslot)<<3)|(bh&7);
// boustrophedon qt per round makes each CU-slot's 4 blocks sum to exactly 66
// k-iterations. bidx&7 = bh&7 -> XCD class, 4 bh/XCD => K/Vt ~2 MB L2-resident.
__global__ __launch_bounds__(256, 4) void attn_mfma_kernel(const bf16* __restrict__ QKV,
                                                           const bf16* __restrict__ Vt,
                                                           bf16* __restrict__ Og, int T) {
    __shared__ __align__(16) bf16 Ps[4 * 16 * 64];  // 8 KB, per-wave XOR-swizzled P
    const int ldq = 3 * D_MODEL;
    int bidx = blockIdx.x;
    int c = bidx & 7;
    int rest = bidx >> 3;           // [0,128)
    int r4 = rest >> 5;             // round 0..3
    int w5 = rest & 31;
    int bhoct = w5 >> 3;            // bh>>3
    int tslot = w5 & 7;
    int bh = bhoct * 8 + c;
    int qt = (r4 & 1) ? (24 - 8 * r4 + tslot) : (31 - 8 * r4 - tslot);
    int h = bh & (NUM_HEADS - 1), b = bh / NUM_HEADS;
    int tid = threadIdx.x;
    int w = tid >> 6, lane = tid & 63;
    int lm = lane & 15, quad = lane >> 4;
    int q0 = qt * 64, qrow0 = q0 + w * 16;

    const bf16* Qp = QKV + ((size_t)(b * T + qrow0 + lm)) * ldq + h * HEAD_SIZE + quad * 8;
    bf16x8 qf0 = *(const bf16x8*)Qp;
    bf16x8 qf1 = *(const bf16x8*)(Qp + 32);

    const bf16* Kbase = QKV + ((size_t)b * T) * ldq + D_MODEL + h * HEAD_SIZE;
    const bf16* Vbase = Vt + ((size_t)b * D_MODEL + h * HEAD_SIZE) * T;
    const float C = 0.1803368801111204f;  // 0.125 * log2(e)
    bf16* PsW = Ps + w * 16 * 64;
    int lm7 = lm & 7;

    f32x4 o[4];
    float m_i[4], l_i[4];
#pragma unroll
    for (int r = 0; r < 4; r++) {
        m_i[r] = -3.0e38f;
        l_i[r] = 0.f;
        o[r] = (f32x4){0.f, 0.f, 0.f, 0.f};
    }

    // prologue: K frags for kt=0
    bf16x8 kcur[8];
#pragma unroll
    for (int jb = 0; jb < 4; jb++) {
        const bf16* kp = Kbase + (size_t)(jb * 16 + lm) * ldq + quad * 8;
        kcur[jb * 2]     = *(const bf16x8*)kp;
        kcur[jb * 2 + 1] = *(const bf16x8*)(kp + 32);
    }

    for (int kt = 0; kt <= qt; kt++) {
        int k0 = kt * 64;
        // V frags early (in flight across QK + softmax)
        bf16x8 vv[8];
#pragma unroll
        for (int db = 0; db < 4; db++) {
            const bf16* vp = Vbase + (size_t)(db * 16 + lm) * T + k0 + quad * 8;
            vv[db * 2]     = *(const bf16x8*)vp;
            vv[db * 2 + 1] = *(const bf16x8*)(vp + 32);
        }
        // S = Q K^T
        f32x4 s[4];
#pragma unroll
        for (int jb = 0; jb < 4; jb++) {
            f32x4 a = {0.f, 0.f, 0.f, 0.f};
            a = __builtin_amdgcn_mfma_f32_16x16x32_bf16(qf0, kcur[jb * 2], a, 0, 0, 0);
            a = __builtin_amdgcn_mfma_f32_16x16x32_bf16(qf1, kcur[jb * 2 + 1], a, 0, 0, 0);
            s[jb] = a;
        }
        // prefetch next K (in flight across softmax + PV)
        bf16x8 knxt[8];
        if (kt < qt) {
#pragma unroll
            for (int jb = 0; jb < 4; jb++) {
                const bf16* kp = Kbase + (size_t)(k0 + 64 + jb * 16 + lm) * ldq + quad * 8;
                knxt[jb * 2]     = *(const bf16x8*)kp;
                knxt[jb * 2 + 1] = *(const bf16x8*)(kp + 32);
            }
        }
        // causal mask (diagonal tile only)
        if (kt == qt) {
#pragma unroll
            for (int jb = 0; jb < 4; jb++)
#pragma unroll
                for (int r = 0; r < 4; r++)
                    if (k0 + jb * 16 + lm > qrow0 + quad * 4 + r) s[jb][r] = -3.0e38f;
        }
        // online softmax
#pragma unroll
        for (int r = 0; r < 4; r++) {
            float mn = fmaxf(fmaxf(s[0][r], s[1][r]), fmaxf(s[2][r], s[3][r]));
            mn = fmaxf(mn, __shfl_xor(mn, 1));
            mn = fmaxf(mn, __shfl_xor(mn, 2));
            mn = fmaxf(mn, __shfl_xor(mn, 4));
            mn = fmaxf(mn, __shfl_xor(mn, 8));
            float mt = fmaxf(m_i[r], mn);
            float alpha = exp2f((m_i[r] - mt) * C);
            m_i[r] = mt;
            float nb = -mt * C;
            float rs = 0.f;
#pragma unroll
            for (int jb = 0; jb < 4; jb++) {
                float p = exp2f(fmaf(s[jb][r], C, nb));
                s[jb][r] = p;
                rs += p;
            }
            rs += __shfl_xor(rs, 1);
            rs += __shfl_xor(rs, 2);
            rs += __shfl_xor(rs, 4);
            rs += __shfl_xor(rs, 8);
            l_i[r] = l_i[r] * alpha + rs;
#pragma unroll
            for (int db = 0; db < 4; db++) o[db][r] *= alpha;
        }
        // P: C/D layout -> LDS (XOR swizzle)
#pragma unroll
        for (int jb = 0; jb < 4; jb++) {
            int g = jb * 2 + (lm >> 3);
#pragma unroll
            for (int r = 0; r < 4; r++) {
                int row = quad * 4 + r;
                PsW[row * 64 + ((g ^ (row & 7)) * 8) + lm7] = (bf16)s[jb][r];
            }
        }
        // O += P V
        bf16x8 pf0 = *(const bf16x8*)&PsW[lm * 64 + ((quad ^ lm7) * 8)];
        bf16x8 pf1 = *(const bf16x8*)&PsW[lm * 64 + (((quad + 4) ^ lm7) * 8)];
#pragma unroll
        for (int db = 0; db < 4; db++) {
            o[db] = __builtin_amdgcn_mfma_f32_16x16x32_bf16(pf0, vv[db * 2], o[db], 0, 0, 0);
            o[db] = __builtin_amdgcn_mfma_f32_16x16x32_bf16(pf1, vv[db * 2 + 1], o[db], 0, 0, 0);
        }
        // rotate K buffers
        if (kt < qt) {
#pragma unroll
            for (int q2 = 0; q2 < 8; q2++) kcur[q2] = knxt[q2];
        }
    }

    // epilogue: O / l -> bf16
    float inv[4];
#pragma unroll
    for (int r = 0; r < 4; r++) inv[r] = 1.f / l_i[r];
    bf16* Ob = Og + ((size_t)(b * T + qrow0 + quad * 4)) * D_MODEL + h * HEAD_SIZE + lm;
#pragma unroll
    for (int r = 0; r < 4; r++)
#pragma unroll
        for (int db = 0; db < 4; db++)
            Ob[(size_t)r * D_MODEL + db * 16] = (bf16)(o[db][r] * inv[r]);
}

extern "C" void kernel_launch(void* const* d_in, const int* in_sizes, int n_in,
                              void* d_out, int out_size, void* d_ws, size_t ws_size,
                              hipStream_t stream) {
    const float* x          = (const float*)d_in[0];
    const float* rms_scale  = (const float*)d_in[1];
    const float* in_proj_w  = (const float*)d_in[2];
    const float* in_proj_b  = (const float*)d_in[3];
    const float* out_proj_w = (const float*)d_in[4];
    const float* out_proj_b = (const float*)d_in[5];
    const float* w1         = (const float*)d_in[6];
    const float* b1         = (const float*)d_in[7];
    const float* w2         = (const float*)d_in[8];
    const float* b2         = (const float*)d_in[9];
    float* out = (float*)d_out;

    const int rows = in_sizes[0] / D_MODEL;  // 4096
    const int T = SEQ_T;
    const int B = rows / T;
    const int D = D_MODEL;

    bf16* inwb  = (bf16*)d_ws;                       // 3M
    bf16* outwb = inwb + (size_t)3 * D * D;          // 1M
    bf16* w1b   = outwb + (size_t)D * D;             // 4M
    bf16* w2b   = w1b + (size_t)4 * D * D;           // 4M
    bf16* XNb   = w2b + (size_t)4 * D * D;           // rows*D (reused as CTXb)
    bf16* RPb   = XNb + (size_t)rows * D;            // rows*D (reused as YNb)
    bf16* QKV   = RPb + (size_t)rows * D;            // rows*3D (H1b spans rows*4D)
    bf16* Vt    = QKV + (size_t)rows * 3 * D;        // rows*D  (tail of H1b region)
    bf16* CTXb  = XNb;
    bf16* YNb   = RPb;
    bf16* H1b   = QKV;

    // 0. cast all weights to bf16 (one kernel)
    {
        int n0 = 3 * D * D, n1 = D * D, n2 = 4 * D * D, n3 = 4 * D * D;
        int tot4 = (n0 + n1 + n2 + n3) / 4;
        cast_all_weights<<<(tot4 + 255) / 256, 256, 0, stream>>>(
            in_proj_w, inwb, n0, out_proj_w, outwb, n1, w1, w1b, n2, w2, w2b, n3);
    }
    // 1+2. fused rmsnorm + rope
    rmsnorm_rope_kernel<<<rows, 256, 0, stream>>>(x, rms_scale, XNb, RPb, T);
    // 3. fused QKV projection; Q/K -> QKV buffer, V -> Vt (transposed)
    {
        dim3 g(3 * D / 128, rows / 128);
        gemm_bf16<0, 0, 1, 1><<<g, 256, 0, stream>>>(RPb, XNb, 2 * D, inwb, in_proj_b,
                                                     nullptr, QKV, Vt, T, rows, 3 * D, D);
    }
    // 4. attention -> CTXb (bf16): 1024 balanced 4-wave blocks
    attn_mfma_kernel<<<B * NUM_HEADS * (T / 64), 256, 0, stream>>>(QKV, Vt, CTXb, T);
    // 5. y = CTXb @ out_proj^T + b -> d_out (fp32), skinny tiles (512 blocks)
    {
        dim3 g(D / 128, rows / 64);
        gemm_bf16_skinny<0><<<g, 256, 0, stream>>>(CTXb, outwb, out_proj_b, out,
                                                   rows, D, D);
    }
    // 6. yn = rmsnorm(y) -> bf16
    rmsnorm_kernel<<<rows, 256, 0, stream>>>(out, rms_scale, YNb);
    // 7. H1b = silu(yn @ w1^T + b1) (bf16)
    {
        dim3 g(4 * D / 128, rows / 128);
        gemm_bf16<1, 0, 1, 0><<<g, 256, 0, stream>>>(YNb, YNb, 4 * D, w1b, b1,
                                                     nullptr, H1b, nullptr, 1, rows, 4 * D, D);
    }
    // 8. out += H1b @ w2^T + b2 (fp32 residual), skinny tiles (512 blocks)
    {
        dim3 g(D / 128, rows / 64);
        gemm_bf16_skinny<1><<<g, 256, 0, stream>>>(H1b, w2b, b2, out,
                                                   rows, D, 4 * D);
    }
}

// Round 9
// 469.288 us; speedup vs baseline: 1.6395x; 1.6395x over previous
//
#include <hip/hip_runtime.h>
#include <math.h>
#include <stdint.h>

#define D_MODEL 1024
#define NUM_HEADS 16
#define HEAD_SIZE 64
#define SEQ_T 2048

typedef __bf16 bf16;
typedef __bf16 bf16x8 __attribute__((ext_vector_type(8)));
typedef float f32x4 __attribute__((ext_vector_type(4)));

__device__ __forceinline__ void gld_lds16(const bf16* g, bf16* l) {
    __builtin_amdgcn_global_load_lds(
        (__attribute__((address_space(1))) void*)(const_cast<bf16*>(g)),
        (__attribute__((address_space(3))) void*)(l), 16, 0, 0);
}

struct __align__(8) b4pack { bf16 v[4]; };

// ---------------- fused f32 -> bf16 cast of all 4 weight matrices ----------------
__global__ __launch_bounds__(256) void cast_all_weights(const float* __restrict__ s0, bf16* __restrict__ d0, int n0,
                                                        const float* __restrict__ s1, bf16* __restrict__ d1, int n1,
                                                        const float* __restrict__ s2, bf16* __restrict__ d2, int n2,
                                                        const float* __restrict__ s3, bf16* __restrict__ d3, int n3) {
    int i = (blockIdx.x * 256 + threadIdx.x) * 4;
    const float* src;
    bf16* dst;
    if (i < n0) { src = s0; dst = d0; }
    else if (i < n0 + n1) { i -= n0; src = s1; dst = d1; }
    else if (i < n0 + n1 + n2) { i -= n0 + n1; src = s2; dst = d2; }
    else { i -= n0 + n1 + n2; if (i >= n3) return; src = s3; dst = d3; }
    float4 v = *(const float4*)(src + i);
    b4pack o;
    o.v[0] = (bf16)v.x; o.v[1] = (bf16)v.y; o.v[2] = (bf16)v.z; o.v[3] = (bf16)v.w;
    *(b4pack*)(dst + i) = o;
}

// ---------------- fused RMSNorm + RoPE ----------------
__global__ __launch_bounds__(256) void rmsnorm_rope_kernel(const float* __restrict__ x,
                                                           const float* __restrict__ scale,
                                                           bf16* __restrict__ xn,
                                                           bf16* __restrict__ rp, int T) {
    __shared__ float red[4];
    int row = blockIdx.x;
    int t = row % T;
    const float* xp = x + (size_t)row * D_MODEL;
    int tid = threadIdx.x;
    float4 xv = *(const float4*)(xp + tid * 4);
    float s = xv.x * xv.x + xv.y * xv.y + xv.z * xv.z + xv.w * xv.w;
    for (int off = 32; off; off >>= 1) s += __shfl_down(s, off);
    if ((tid & 63) == 0) red[tid >> 6] = s;
    __syncthreads();
    if (tid == 0) red[0] = red[0] + red[1] + red[2] + red[3];
    __syncthreads();
    float inv = rsqrtf(red[0] * (1.0f / D_MODEL) + 1e-6f);
    float4 sc = *(const float4*)(scale + tid * 4);
    float n0 = xv.x * inv * sc.x, n1 = xv.y * inv * sc.y;
    float n2 = xv.z * inv * sc.z, n3 = xv.w * inv * sc.w;
    b4pack pn;
    pn.v[0] = (bf16)n0; pn.v[1] = (bf16)n1; pn.v[2] = (bf16)n2; pn.v[3] = (bf16)n3;
    *(b4pack*)(xn + (size_t)row * D_MODEL + tid * 4) = pn;
    int p0 = 2 * tid;
    float th0 = expf(-0.2878231366242557f * (float)(p0 & 31));        // ln(10000)/32
    float th1 = expf(-0.2878231366242557f * (float)((p0 + 1) & 31));
    float s0, c0, s1, c1;
    sincosf((float)t * th0, &s0, &c0);
    sincosf((float)t * th1, &s1, &c1);
    b4pack pr;
    pr.v[0] = (bf16)(n0 * c0 - n1 * s0);
    pr.v[1] = (bf16)(n1 * c0 + n0 * s0);
    pr.v[2] = (bf16)(n2 * c1 - n3 * s1);
    pr.v[3] = (bf16)(n3 * c1 + n2 * s1);
    *(b4pack*)(rp + (size_t)row * D_MODEL + tid * 4) = pr;
}

// ---------------- RMSNorm only ----------------
__global__ __launch_bounds__(256) void rmsnorm_kernel(const float* __restrict__ x,
                                                      const float* __restrict__ scale,
                                                      bf16* __restrict__ out) {
    __shared__ float red[4];
    int row = blockIdx.x;
    const float* xp = x + (size_t)row * D_MODEL;
    bf16* op = out + (size_t)row * D_MODEL;
    int tid = threadIdx.x;
    float s = 0.f;
    for (int i = tid; i < D_MODEL; i += 256) { float v = xp[i]; s += v * v; }
    for (int off = 32; off; off >>= 1) s += __shfl_down(s, off);
    if ((tid & 63) == 0) red[tid >> 6] = s;
    __syncthreads();
    if (tid == 0) red[0] = red[0] + red[1] + red[2] + red[3];
    __syncthreads();
    float inv = rsqrtf(red[0] * (1.0f / D_MODEL) + 1e-6f);
    for (int i = tid; i < D_MODEL; i += 256) op[i] = (bf16)(xp[i] * inv * scale[i]);
}

// ---------------- bf16 MFMA GEMM, 128x128 tile (m97 structure) ----------------
template <int ACT, int ADD, int OUT_BF16, int VT>
__global__ __launch_bounds__(256) void gemm_bf16(const bf16* __restrict__ A,
                                                 const bf16* __restrict__ A2, int splitN,
                                                 const bf16* __restrict__ W,
                                                 const float* __restrict__ bias,
                                                 float* __restrict__ Cf,
                                                 bf16* __restrict__ Cb,
                                                 bf16* __restrict__ Vtp, int Tlen,
                                                 int M, int N, int K) {
    __shared__ __align__(16) bf16 As[128 * 32];
    __shared__ __align__(16) bf16 Bs[128 * 32];
    int tid = threadIdx.x;
    int m0 = blockIdx.y * 128, n0 = blockIdx.x * 128;
    const bf16* Ag = (n0 < splitN) ? A : A2;

    int lane = tid & 63, w = tid >> 6;
    int wm = w >> 1, wn = w & 1;
    int lm = lane & 15, quad = lane >> 4;

    int c0 = tid, c1 = tid + 256;
    int ar0 = c0 >> 2, ak0 = (c0 & 3) * 8;
    int ar1 = c1 >> 2, ak1 = (c1 & 3) * 8;

    f32x4 acc[4][4];
#pragma unroll
    for (int i = 0; i < 4; i++)
#pragma unroll
        for (int j = 0; j < 4; j++)
#pragma unroll
            for (int r = 0; r < 4; r++) acc[i][j][r] = 0.f;

    int abase = (wm * 64 + lm) * 32 + quad * 8;
    int bbase = (wn * 64 + lm) * 32 + quad * 8;

    for (int k0 = 0; k0 < K; k0 += 32) {
        __syncthreads();
        gld_lds16(Ag + (size_t)(m0 + ar0) * K + k0 + ak0, As + c0 * 8);
        gld_lds16(Ag + (size_t)(m0 + ar1) * K + k0 + ak1, As + c1 * 8);
        gld_lds16(W  + (size_t)(n0 + ar0) * K + k0 + ak0, Bs + c0 * 8);
        gld_lds16(W  + (size_t)(n0 + ar1) * K + k0 + ak1, Bs + c1 * 8);
        __syncthreads();
        bf16x8 af[4], bfr[4];
#pragma unroll
        for (int i = 0; i < 4; i++) af[i] = *(const bf16x8*)&As[abase + i * 16 * 32];
#pragma unroll
        for (int j = 0; j < 4; j++) bfr[j] = *(const bf16x8*)&Bs[bbase + j * 16 * 32];
#pragma unroll
        for (int i = 0; i < 4; i++)
#pragma unroll
            for (int j = 0; j < 4; j++)
                acc[i][j] = __builtin_amdgcn_mfma_f32_16x16x32_bf16(af[i], bfr[j], acc[i][j], 0, 0, 0);
    }

    if (VT && n0 >= 2 * D_MODEL) {
#pragma unroll
        for (int j = 0; j < 4; j++) {
            int col = n0 + wn * 64 + j * 16 + lm;
            int dimg = col - 2 * D_MODEL;
            float bv = bias[col];
#pragma unroll
            for (int i = 0; i < 4; i++) {
                int row0 = m0 + wm * 64 + i * 16 + quad * 4;
                int bb = row0 / Tlen, t0 = row0 % Tlen;
                b4pack pk;
#pragma unroll
                for (int r = 0; r < 4; r++) pk.v[r] = (bf16)(acc[i][j][r] + bv);
                *(b4pack*)(Vtp + ((size_t)bb * D_MODEL + dimg) * Tlen + t0) = pk;
            }
        }
        return;
    }

#pragma unroll
    for (int j = 0; j < 4; j++) {
        int col = n0 + wn * 64 + j * 16 + lm;
        float bv = bias[col];
#pragma unroll
        for (int i = 0; i < 4; i++) {
#pragma unroll
            for (int r = 0; r < 4; r++) {
                int row = m0 + wm * 64 + i * 16 + quad * 4 + r;
                float v = acc[i][j][r] + bv;
                if (ACT == 1) v = v / (1.f + __expf(-v));
                size_t idx = (size_t)row * N + col;
                if (ADD) v += Cf[idx];
                if (OUT_BF16) Cb[idx] = (bf16)v;
                else Cf[idx] = v;
            }
        }
    }
}

// ---------------- skinny bf16 MFMA GEMM, 64x128 tile (for N=1024 GEMMs) -------------
template <int ADD>
__global__ __launch_bounds__(256) void gemm_bf16_skinny(const bf16* __restrict__ A,
                                                        const bf16* __restrict__ W,
                                                        const float* __restrict__ bias,
                                                        float* __restrict__ Cf,
                                                        int M, int N, int K) {
    __shared__ __align__(16) bf16 As[64 * 32];   // 4 KB
    __shared__ __align__(16) bf16 Bs[128 * 32];  // 8 KB
    int tid = threadIdx.x;
    int m0 = blockIdx.y * 64, n0 = blockIdx.x * 128;

    int lane = tid & 63, w = tid >> 6;
    int lm = lane & 15, quad = lane >> 4;

    int ar = tid >> 2, ak = (tid & 3) * 8;         // A: 256 chunks
    int c1 = tid + 256;
    int br1 = c1 >> 2, bk1 = (c1 & 3) * 8;         // B: 512 chunks

    f32x4 acc[8];
#pragma unroll
    for (int j = 0; j < 8; j++)
#pragma unroll
        for (int r = 0; r < 4; r++) acc[j][r] = 0.f;

    int abase = (w * 16 + lm) * 32 + quad * 8;
    int bbase = lm * 32 + quad * 8;

    for (int k0 = 0; k0 < K; k0 += 32) {
        __syncthreads();
        gld_lds16(A + (size_t)(m0 + ar) * K + k0 + ak, As + tid * 8);
        gld_lds16(W + (size_t)(n0 + ar) * K + k0 + ak, Bs + tid * 8);
        gld_lds16(W + (size_t)(n0 + br1) * K + k0 + bk1, Bs + c1 * 8);
        __syncthreads();
        bf16x8 af = *(const bf16x8*)&As[abase];
#pragma unroll
        for (int j = 0; j < 8; j++) {
            bf16x8 bfr = *(const bf16x8*)&Bs[bbase + j * 16 * 32];
            acc[j] = __builtin_amdgcn_mfma_f32_16x16x32_bf16(af, bfr, acc[j], 0, 0, 0);
        }
    }

#pragma unroll
    for (int j = 0; j < 8; j++) {
        int col = n0 + j * 16 + lm;
        float bv = bias[col];
#pragma unroll
        for (int r = 0; r < 4; r++) {
            int row = m0 + w * 16 + quad * 4 + r;
            float v = acc[j][r] + bv;
            size_t idx = (size_t)row * N + col;
            if (ADD) v += Cf[idx];
            Cf[idx] = v;
        }
    }
}

// ---------------- MFMA flash attention: 4-wave blocks, 4-round balanced grid --------
// 1024 blocks. bidx = ((r*32 + (bh>>3)*8 + tslot)<<3)|(bh&7); boustrophedon qt per
// round: each CU-slot's 4 blocks sum to exactly 66 k-iterations. bidx&7 = bh&7 ->
// XCD class, 4 bh/XCD => K/Vt ~2 MB L2-resident. NO min-waves clamp: R8 showed
// __launch_bounds__(256,4) forces VGPR=64 -> fragment spill storm (727 MB scratch
// writes, 2.7x slower). Natural allocation is ~124 VGPR = 4 waves/SIMD anyway.
__global__ __launch_bounds__(256) void attn_mfma_kernel(const bf16* __restrict__ QKV,
                                                        const bf16* __restrict__ Vt,
                                                        bf16* __restrict__ Og, int T) {
    __shared__ __align__(16) bf16 Ps[4 * 16 * 64];  // 8 KB, per-wave XOR-swizzled P
    const int ldq = 3 * D_MODEL;
    int bidx = blockIdx.x;
    int c = bidx & 7;
    int rest = bidx >> 3;           // [0,128)
    int r4 = rest >> 5;             // round 0..3
    int w5 = rest & 31;
    int bhoct = w5 >> 3;            // bh>>3
    int tslot = w5 & 7;
    int bh = bhoct * 8 + c;
    int qt = (r4 & 1) ? (24 - 8 * r4 + tslot) : (31 - 8 * r4 - tslot);
    int h = bh & (NUM_HEADS - 1), b = bh / NUM_HEADS;
    int tid = threadIdx.x;
    int w = tid >> 6, lane = tid & 63;
    int lm = lane & 15, quad = lane >> 4;
    int q0 = qt * 64, qrow0 = q0 + w * 16;

    const bf16* Qp = QKV + ((size_t)(b * T + qrow0 + lm)) * ldq + h * HEAD_SIZE + quad * 8;
    bf16x8 qf0 = *(const bf16x8*)Qp;
    bf16x8 qf1 = *(const bf16x8*)(Qp + 32);

    const bf16* Kbase = QKV + ((size_t)b * T) * ldq + D_MODEL + h * HEAD_SIZE;
    const bf16* Vbase = Vt + ((size_t)b * D_MODEL + h * HEAD_SIZE) * T;
    const float C = 0.1803368801111204f;  // 0.125 * log2(e)
    bf16* PsW = Ps + w * 16 * 64;
    int lm7 = lm & 7;

    f32x4 o[4];
    float m_i[4], l_i[4];
#pragma unroll
    for (int r = 0; r < 4; r++) {
        m_i[r] = -3.0e38f;
        l_i[r] = 0.f;
        o[r] = (f32x4){0.f, 0.f, 0.f, 0.f};
    }

    // prologue: K frags for kt=0
    bf16x8 kcur[8];
#pragma unroll
    for (int jb = 0; jb < 4; jb++) {
        const bf16* kp = Kbase + (size_t)(jb * 16 + lm) * ldq + quad * 8;
        kcur[jb * 2]     = *(const bf16x8*)kp;
        kcur[jb * 2 + 1] = *(const bf16x8*)(kp + 32);
    }

    for (int kt = 0; kt <= qt; kt++) {
        int k0 = kt * 64;
        // V frags early (in flight across QK + softmax)
        bf16x8 vv[8];
#pragma unroll
        for (int db = 0; db < 4; db++) {
            const bf16* vp = Vbase + (size_t)(db * 16 + lm) * T + k0 + quad * 8;
            vv[db * 2]     = *(const bf16x8*)vp;
            vv[db * 2 + 1] = *(const bf16x8*)(vp + 32);
        }
        // S = Q K^T
        f32x4 s[4];
#pragma unroll
        for (int jb = 0; jb < 4; jb++) {
            f32x4 a = {0.f, 0.f, 0.f, 0.f};
            a = __builtin_amdgcn_mfma_f32_16x16x32_bf16(qf0, kcur[jb * 2], a, 0, 0, 0);
            a = __builtin_amdgcn_mfma_f32_16x16x32_bf16(qf1, kcur[jb * 2 + 1], a, 0, 0, 0);
            s[jb] = a;
        }
        // prefetch next K (in flight across softmax + PV)
        bf16x8 knxt[8];
        if (kt < qt) {
#pragma unroll
            for (int jb = 0; jb < 4; jb++) {
                const bf16* kp = Kbase + (size_t)(k0 + 64 + jb * 16 + lm) * ldq + quad * 8;
                knxt[jb * 2]     = *(const bf16x8*)kp;
                knxt[jb * 2 + 1] = *(const bf16x8*)(kp + 32);
            }
        }
        // causal mask (diagonal tile only)
        if (kt == qt) {
#pragma unroll
            for (int jb = 0; jb < 4; jb++)
#pragma unroll
                for (int r = 0; r < 4; r++)
                    if (k0 + jb * 16 + lm > qrow0 + quad * 4 + r) s[jb][r] = -3.0e38f;
        }
        // online softmax
#pragma unroll
        for (int r = 0; r < 4; r++) {
            float mn = fmaxf(fmaxf(s[0][r], s[1][r]), fmaxf(s[2][r], s[3][r]));
            mn = fmaxf(mn, __shfl_xor(mn, 1));
            mn = fmaxf(mn, __shfl_xor(mn, 2));
            mn = fmaxf(mn, __shfl_xor(mn, 4));
            mn = fmaxf(mn, __shfl_xor(mn, 8));
            float mt = fmaxf(m_i[r], mn);
            float alpha = exp2f((m_i[r] - mt) * C);
            m_i[r] = mt;
            float nb = -mt * C;
            float rs = 0.f;
#pragma unroll
            for (int jb = 0; jb < 4; jb++) {
                float p = exp2f(fmaf(s[jb][r], C, nb));
                s[jb][r] = p;
                rs += p;
            }
            rs += __shfl_xor(rs, 1);
            rs += __shfl_xor(rs, 2);
            rs += __shfl_xor(rs, 4);
            rs += __shfl_xor(rs, 8);
            l_i[r] = l_i[r] * alpha + rs;
#pragma unroll
            for (int db = 0; db < 4; db++) o[db][r] *= alpha;
        }
        // P: C/D layout -> LDS (XOR swizzle)
#pragma unroll
        for (int jb = 0; jb < 4; jb++) {
            int g = jb * 2 + (lm >> 3);
#pragma unroll
            for (int r = 0; r < 4; r++) {
                int row = quad * 4 + r;
                PsW[row * 64 + ((g ^ (row & 7)) * 8) + lm7] = (bf16)s[jb][r];
            }
        }
        // O += P V
        bf16x8 pf0 = *(const bf16x8*)&PsW[lm * 64 + ((quad ^ lm7) * 8)];
        bf16x8 pf1 = *(const bf16x8*)&PsW[lm * 64 + (((quad + 4) ^ lm7) * 8)];
#pragma unroll
        for (int db = 0; db < 4; db++) {
            o[db] = __builtin_amdgcn_mfma_f32_16x16x32_bf16(pf0, vv[db * 2], o[db], 0, 0, 0);
            o[db] = __builtin_amdgcn_mfma_f32_16x16x32_bf16(pf1, vv[db * 2 + 1], o[db], 0, 0, 0);
        }
        // rotate K buffers
        if (kt < qt) {
#pragma unroll
            for (int q2 = 0; q2 < 8; q2++) kcur[q2] = knxt[q2];
        }
    }

    // epilogue: O / l -> bf16
    float inv[4];
#pragma unroll
    for (int r = 0; r < 4; r++) inv[r] = 1.f / l_i[r];
    bf16* Ob = Og + ((size_t)(b * T + qrow0 + quad * 4)) * D_MODEL + h * HEAD_SIZE + lm;
#pragma unroll
    for (int r = 0; r < 4; r++)
#pragma unroll
        for (int db = 0; db < 4; db++)
            Ob[(size_t)r * D_MODEL + db * 16] = (bf16)(o[db][r] * inv[r]);
}

extern "C" void kernel_launch(void* const* d_in, const int* in_sizes, int n_in,
                              void* d_out, int out_size, void* d_ws, size_t ws_size,
                              hipStream_t stream) {
    const float* x          = (const float*)d_in[0];
    const float* rms_scale  = (const float*)d_in[1];
    const float* in_proj_w  = (const float*)d_in[2];
    const float* in_proj_b  = (const float*)d_in[3];
    const float* out_proj_w = (const float*)d_in[4];
    const float* out_proj_b = (const float*)d_in[5];
    const float* w1         = (const float*)d_in[6];
    const float* b1         = (const float*)d_in[7];
    const float* w2         = (const float*)d_in[8];
    const float* b2         = (const float*)d_in[9];
    float* out = (float*)d_out;

    const int rows = in_sizes[0] / D_MODEL;  // 4096
    const int T = SEQ_T;
    const int B = rows / T;
    const int D = D_MODEL;

    bf16* inwb  = (bf16*)d_ws;                       // 3M
    bf16* outwb = inwb + (size_t)3 * D * D;          // 1M
    bf16* w1b   = outwb + (size_t)D * D;             // 4M
    bf16* w2b   = w1b + (size_t)4 * D * D;           // 4M
    bf16* XNb   = w2b + (size_t)4 * D * D;           // rows*D (reused as CTXb)
    bf16* RPb   = XNb + (size_t)rows * D;            // rows*D (reused as YNb)
    bf16* QKV   = RPb + (size_t)rows * D;            // rows*3D (H1b spans rows*4D)
    bf16* Vt    = QKV + (size_t)rows * 3 * D;        // rows*D  (tail of H1b region)
    bf16* CTXb  = XNb;
    bf16* YNb   = RPb;
    bf16* H1b   = QKV;

    // 0. cast all weights to bf16 (one kernel)
    {
        int n0 = 3 * D * D, n1 = D * D, n2 = 4 * D * D, n3 = 4 * D * D;
        int tot4 = (n0 + n1 + n2 + n3) / 4;
        cast_all_weights<<<(tot4 + 255) / 256, 256, 0, stream>>>(
            in_proj_w, inwb, n0, out_proj_w, outwb, n1, w1, w1b, n2, w2, w2b, n3);
    }
    // 1+2. fused rmsnorm + rope
    rmsnorm_rope_kernel<<<rows, 256, 0, stream>>>(x, rms_scale, XNb, RPb, T);
    // 3. fused QKV projection; Q/K -> QKV buffer, V -> Vt (transposed)
    {
        dim3 g(3 * D / 128, rows / 128);
        gemm_bf16<0, 0, 1, 1><<<g, 256, 0, stream>>>(RPb, XNb, 2 * D, inwb, in_proj_b,
                                                     nullptr, QKV, Vt, T, rows, 3 * D, D);
    }
    // 4. attention -> CTXb (bf16): 1024 balanced 4-wave blocks
    attn_mfma_kernel<<<B * NUM_HEADS * (T / 64), 256, 0, stream>>>(QKV, Vt, CTXb, T);
    // 5. y = CTXb @ out_proj^T + b -> d_out (fp32), skinny tiles (512 blocks)
    {
        dim3 g(D / 128, rows / 64);
        gemm_bf16_skinny<0><<<g, 256, 0, stream>>>(CTXb, outwb, out_proj_b, out,
                                                   rows, D, D);
    }
    // 6. yn = rmsnorm(y) -> bf16
    rmsnorm_kernel<<<rows, 256, 0, stream>>>(out, rms_scale, YNb);
    // 7. H1b = silu(yn @ w1^T + b1) (bf16)
    {
        dim3 g(4 * D / 128, rows / 128);
        gemm_bf16<1, 0, 1, 0><<<g, 256, 0, stream>>>(YNb, YNb, 4 * D, w1b, b1,
                                                     nullptr, H1b, nullptr, 1, rows, 4 * D, D);
    }
    // 8. out += H1b @ w2^T + b2 (fp32 residual), skinny tiles (512 blocks)
    {
        dim3 g(D / 128, rows / 64);
        gemm_bf16_skinny<1><<<g, 256, 0, stream>>>(H1b, w2b, b2, out,
                                                   rows, D, 4 * D);
    }
}

// Round 10
// 424.068 us; speedup vs baseline: 1.8144x; 1.1066x over previous
//
#include <hip/hip_runtime.h>
#include <math.h>
#include <stdint.h>

#define D_MODEL 1024
#define NUM_HEADS 16
#define HEAD_SIZE 64
#define SEQ_T 2048

typedef __bf16 bf16;
typedef __bf16 bf16x8 __attribute__((ext_vector_type(8)));
typedef float f32x4 __attribute__((ext_vector_type(4)));

__device__ __forceinline__ void gld_lds16(const bf16* g, bf16* l) {
    __builtin_amdgcn_global_load_lds(
        (__attribute__((address_space(1))) void*)(const_cast<bf16*>(g)),
        (__attribute__((address_space(3))) void*)(l), 16, 0, 0);
}

struct __align__(8) b4pack { bf16 v[4]; };

// ---------------- fused f32 -> bf16 cast of all 4 weight matrices ----------------
__global__ __launch_bounds__(256) void cast_all_weights(const float* __restrict__ s0, bf16* __restrict__ d0, int n0,
                                                        const float* __restrict__ s1, bf16* __restrict__ d1, int n1,
                                                        const float* __restrict__ s2, bf16* __restrict__ d2, int n2,
                                                        const float* __restrict__ s3, bf16* __restrict__ d3, int n3) {
    int i = (blockIdx.x * 256 + threadIdx.x) * 4;
    const float* src;
    bf16* dst;
    if (i < n0) { src = s0; dst = d0; }
    else if (i < n0 + n1) { i -= n0; src = s1; dst = d1; }
    else if (i < n0 + n1 + n2) { i -= n0 + n1; src = s2; dst = d2; }
    else { i -= n0 + n1 + n2; if (i >= n3) return; src = s3; dst = d3; }
    float4 v = *(const float4*)(src + i);
    b4pack o;
    o.v[0] = (bf16)v.x; o.v[1] = (bf16)v.y; o.v[2] = (bf16)v.z; o.v[3] = (bf16)v.w;
    *(b4pack*)(dst + i) = o;
}

// ---------------- fused RMSNorm + RoPE ----------------
__global__ __launch_bounds__(256) void rmsnorm_rope_kernel(const float* __restrict__ x,
                                                           const float* __restrict__ scale,
                                                           bf16* __restrict__ xn,
                                                           bf16* __restrict__ rp, int T) {
    __shared__ float red[4];
    int row = blockIdx.x;
    int t = row % T;
    const float* xp = x + (size_t)row * D_MODEL;
    int tid = threadIdx.x;
    float4 xv = *(const float4*)(xp + tid * 4);
    float s = xv.x * xv.x + xv.y * xv.y + xv.z * xv.z + xv.w * xv.w;
    for (int off = 32; off; off >>= 1) s += __shfl_down(s, off);
    if ((tid & 63) == 0) red[tid >> 6] = s;
    __syncthreads();
    if (tid == 0) red[0] = red[0] + red[1] + red[2] + red[3];
    __syncthreads();
    float inv = rsqrtf(red[0] * (1.0f / D_MODEL) + 1e-6f);
    float4 sc = *(const float4*)(scale + tid * 4);
    float n0 = xv.x * inv * sc.x, n1 = xv.y * inv * sc.y;
    float n2 = xv.z * inv * sc.z, n3 = xv.w * inv * sc.w;
    b4pack pn;
    pn.v[0] = (bf16)n0; pn.v[1] = (bf16)n1; pn.v[2] = (bf16)n2; pn.v[3] = (bf16)n3;
    *(b4pack*)(xn + (size_t)row * D_MODEL + tid * 4) = pn;
    int p0 = 2 * tid;
    float th0 = expf(-0.2878231366242557f * (float)(p0 & 31));        // ln(10000)/32
    float th1 = expf(-0.2878231366242557f * (float)((p0 + 1) & 31));
    float s0, c0, s1, c1;
    sincosf((float)t * th0, &s0, &c0);
    sincosf((float)t * th1, &s1, &c1);
    b4pack pr;
    pr.v[0] = (bf16)(n0 * c0 - n1 * s0);
    pr.v[1] = (bf16)(n1 * c0 + n0 * s0);
    pr.v[2] = (bf16)(n2 * c1 - n3 * s1);
    pr.v[3] = (bf16)(n3 * c1 + n2 * s1);
    *(b4pack*)(rp + (size_t)row * D_MODEL + tid * 4) = pr;
}

// ---------------- RMSNorm only ----------------
__global__ __launch_bounds__(256) void rmsnorm_kernel(const float* __restrict__ x,
                                                      const float* __restrict__ scale,
                                                      bf16* __restrict__ out) {
    __shared__ float red[4];
    int row = blockIdx.x;
    const float* xp = x + (size_t)row * D_MODEL;
    bf16* op = out + (size_t)row * D_MODEL;
    int tid = threadIdx.x;
    float s = 0.f;
    for (int i = tid; i < D_MODEL; i += 256) { float v = xp[i]; s += v * v; }
    for (int off = 32; off; off >>= 1) s += __shfl_down(s, off);
    if ((tid & 63) == 0) red[tid >> 6] = s;
    __syncthreads();
    if (tid == 0) red[0] = red[0] + red[1] + red[2] + red[3];
    __syncthreads();
    float inv = rsqrtf(red[0] * (1.0f / D_MODEL) + 1e-6f);
    for (int i = tid; i < D_MODEL; i += 256) op[i] = (bf16)(xp[i] * inv * scale[i]);
}

// ---------------- bf16 MFMA GEMM, 128x128 tile (m97 structure) ----------------
template <int ACT, int ADD, int OUT_BF16, int VT>
__global__ __launch_bounds__(256) void gemm_bf16(const bf16* __restrict__ A,
                                                 const bf16* __restrict__ A2, int splitN,
                                                 const bf16* __restrict__ W,
                                                 const float* __restrict__ bias,
                                                 float* __restrict__ Cf,
                                                 bf16* __restrict__ Cb,
                                                 bf16* __restrict__ Vtp, int Tlen,
                                                 int M, int N, int K) {
    __shared__ __align__(16) bf16 As[128 * 32];
    __shared__ __align__(16) bf16 Bs[128 * 32];
    int tid = threadIdx.x;
    int m0 = blockIdx.y * 128, n0 = blockIdx.x * 128;
    const bf16* Ag = (n0 < splitN) ? A : A2;

    int lane = tid & 63, w = tid >> 6;
    int wm = w >> 1, wn = w & 1;
    int lm = lane & 15, quad = lane >> 4;

    int c0 = tid, c1 = tid + 256;
    int ar0 = c0 >> 2, ak0 = (c0 & 3) * 8;
    int ar1 = c1 >> 2, ak1 = (c1 & 3) * 8;

    f32x4 acc[4][4];
#pragma unroll
    for (int i = 0; i < 4; i++)
#pragma unroll
        for (int j = 0; j < 4; j++)
#pragma unroll
            for (int r = 0; r < 4; r++) acc[i][j][r] = 0.f;

    int abase = (wm * 64 + lm) * 32 + quad * 8;
    int bbase = (wn * 64 + lm) * 32 + quad * 8;

    for (int k0 = 0; k0 < K; k0 += 32) {
        __syncthreads();
        gld_lds16(Ag + (size_t)(m0 + ar0) * K + k0 + ak0, As + c0 * 8);
        gld_lds16(Ag + (size_t)(m0 + ar1) * K + k0 + ak1, As + c1 * 8);
        gld_lds16(W  + (size_t)(n0 + ar0) * K + k0 + ak0, Bs + c0 * 8);
        gld_lds16(W  + (size_t)(n0 + ar1) * K + k0 + ak1, Bs + c1 * 8);
        __syncthreads();
        bf16x8 af[4], bfr[4];
#pragma unroll
        for (int i = 0; i < 4; i++) af[i] = *(const bf16x8*)&As[abase + i * 16 * 32];
#pragma unroll
        for (int j = 0; j < 4; j++) bfr[j] = *(const bf16x8*)&Bs[bbase + j * 16 * 32];
#pragma unroll
        for (int i = 0; i < 4; i++)
#pragma unroll
            for (int j = 0; j < 4; j++)
                acc[i][j] = __builtin_amdgcn_mfma_f32_16x16x32_bf16(af[i], bfr[j], acc[i][j], 0, 0, 0);
    }

    if (VT && n0 >= 2 * D_MODEL) {
#pragma unroll
        for (int j = 0; j < 4; j++) {
            int col = n0 + wn * 64 + j * 16 + lm;
            int dimg = col - 2 * D_MODEL;
            float bv = bias[col];
#pragma unroll
            for (int i = 0; i < 4; i++) {
                int row0 = m0 + wm * 64 + i * 16 + quad * 4;
                int bb = row0 / Tlen, t0 = row0 % Tlen;
                b4pack pk;
#pragma unroll
                for (int r = 0; r < 4; r++) pk.v[r] = (bf16)(acc[i][j][r] + bv);
                *(b4pack*)(Vtp + ((size_t)bb * D_MODEL + dimg) * Tlen + t0) = pk;
            }
        }
        return;
    }

#pragma unroll
    for (int j = 0; j < 4; j++) {
        int col = n0 + wn * 64 + j * 16 + lm;
        float bv = bias[col];
#pragma unroll
        for (int i = 0; i < 4; i++) {
#pragma unroll
            for (int r = 0; r < 4; r++) {
                int row = m0 + wm * 64 + i * 16 + quad * 4 + r;
                float v = acc[i][j][r] + bv;
                if (ACT == 1) v = v / (1.f + __expf(-v));
                size_t idx = (size_t)row * N + col;
                if (ADD) v += Cf[idx];
                if (OUT_BF16) Cb[idx] = (bf16)v;
                else Cf[idx] = v;
            }
        }
    }
}

// ---------------- skinny bf16 MFMA GEMM, 64x128 tile (for N=1024 GEMMs) -------------
template <int ADD>
__global__ __launch_bounds__(256) void gemm_bf16_skinny(const bf16* __restrict__ A,
                                                        const bf16* __restrict__ W,
                                                        const float* __restrict__ bias,
                                                        float* __restrict__ Cf,
                                                        int M, int N, int K) {
    __shared__ __align__(16) bf16 As[64 * 32];   // 4 KB
    __shared__ __align__(16) bf16 Bs[128 * 32];  // 8 KB
    int tid = threadIdx.x;
    int m0 = blockIdx.y * 64, n0 = blockIdx.x * 128;

    int lane = tid & 63, w = tid >> 6;
    int lm = lane & 15, quad = lane >> 4;

    int ar = tid >> 2, ak = (tid & 3) * 8;         // A: 256 chunks
    int c1 = tid + 256;
    int br1 = c1 >> 2, bk1 = (c1 & 3) * 8;         // B: 512 chunks

    f32x4 acc[8];
#pragma unroll
    for (int j = 0; j < 8; j++)
#pragma unroll
        for (int r = 0; r < 4; r++) acc[j][r] = 0.f;

    int abase = (w * 16 + lm) * 32 + quad * 8;
    int bbase = lm * 32 + quad * 8;

    for (int k0 = 0; k0 < K; k0 += 32) {
        __syncthreads();
        gld_lds16(A + (size_t)(m0 + ar) * K + k0 + ak, As + tid * 8);
        gld_lds16(W + (size_t)(n0 + ar) * K + k0 + ak, Bs + tid * 8);
        gld_lds16(W + (size_t)(n0 + br1) * K + k0 + bk1, Bs + c1 * 8);
        __syncthreads();
        bf16x8 af = *(const bf16x8*)&As[abase];
#pragma unroll
        for (int j = 0; j < 8; j++) {
            bf16x8 bfr = *(const bf16x8*)&Bs[bbase + j * 16 * 32];
            acc[j] = __builtin_amdgcn_mfma_f32_16x16x32_bf16(af, bfr, acc[j], 0, 0, 0);
        }
    }

#pragma unroll
    for (int j = 0; j < 8; j++) {
        int col = n0 + j * 16 + lm;
        float bv = bias[col];
#pragma unroll
        for (int r = 0; r < 4; r++) {
            int row = m0 + w * 16 + quad * 4 + r;
            float v = acc[j][r] + bv;
            size_t idx = (size_t)row * N + col;
            if (ADD) v += Cf[idx];
            Cf[idx] = v;
        }
    }
}

// ---------------- MFMA flash attention: LDS-staged K/V tiles (m97-style) ------------
// All 4 waves share one K-tile + one V-tile per iteration, staged via async
// global_load_lds (no VGPR cost, 4x less L2 traffic than per-wave fragment loads
// — R9 showed per-wave K/V frags cost ~96 VGPRs -> 2 waves/SIMD and ~80% stall).
// LDS dest of global_load_lds is lane-ordered, so the bank-XOR swizzle is applied
// to the SOURCE chunk index: slot s holds row r=s>>3, chunk c=(s&7)^(r&7).
// Fragment reads: slot = n*8 + (q ^ (n&7)) -> conflict-free (<=2-way).
// 24 KB LDS, ~VGPR 80 -> 4+ blocks/CU. 1024-block 4-round balanced grid (R9).
__global__ __launch_bounds__(256) void attn_mfma_kernel(const bf16* __restrict__ QKV,
                                                        const bf16* __restrict__ Vt,
                                                        bf16* __restrict__ Og, int T) {
    __shared__ __align__(16) bf16 Ks[64 * 64];      // 8 KB: row=token, swizzled chunks
    __shared__ __align__(16) bf16 Vs[64 * 64];      // 8 KB: row=dim, swizzled token-chunks
    __shared__ __align__(16) bf16 Ps[4 * 16 * 64];  // 8 KB, per-wave XOR-swizzled P
    const int ldq = 3 * D_MODEL;
    int bidx = blockIdx.x;
    int c = bidx & 7;
    int rest = bidx >> 3;           // [0,128)
    int r4 = rest >> 5;             // round 0..3
    int w5 = rest & 31;
    int bhoct = w5 >> 3;            // bh>>3
    int tslot = w5 & 7;
    int bh = bhoct * 8 + c;
    int qt = (r4 & 1) ? (24 - 8 * r4 + tslot) : (31 - 8 * r4 - tslot);
    int h = bh & (NUM_HEADS - 1), b = bh / NUM_HEADS;
    int tid = threadIdx.x;
    int w = tid >> 6, lane = tid & 63;
    int lm = lane & 15, quad = lane >> 4;
    int q0 = qt * 64, qrow0 = q0 + w * 16;

    // staging chunk ids: 512 x 16B chunks per tile, thread handles s0=tid, s1=tid+256
    int s0 = tid, s1 = tid + 256;
    int sr0 = s0 >> 3, sc0 = (s0 & 7) ^ (sr0 & 7);
    int sr1 = s1 >> 3, sc1 = (s1 & 7) ^ (sr1 & 7);

    const bf16* Qp = QKV + ((size_t)(b * T + qrow0 + lm)) * ldq + h * HEAD_SIZE + quad * 8;
    bf16x8 qf0 = *(const bf16x8*)Qp;
    bf16x8 qf1 = *(const bf16x8*)(Qp + 32);

    const bf16* Kbase = QKV + ((size_t)b * T) * ldq + D_MODEL + h * HEAD_SIZE;
    const bf16* Vbase = Vt + ((size_t)b * D_MODEL + h * HEAD_SIZE) * T;
    const float C = 0.1803368801111204f;  // 0.125 * log2(e)
    bf16* PsW = Ps + w * 16 * 64;
    int lm7 = lm & 7;

    f32x4 o[4];
    float m_i[4], l_i[4];
#pragma unroll
    for (int r = 0; r < 4; r++) {
        m_i[r] = -3.0e38f;
        l_i[r] = 0.f;
        o[r] = (f32x4){0.f, 0.f, 0.f, 0.f};
    }

    for (int kt = 0; kt <= qt; kt++) {
        int k0 = kt * 64;
        __syncthreads();  // prev-iter LDS reads complete
        // stage shared K tile (row=token) and V tile (row=dim), source-swizzled
        gld_lds16(Kbase + (size_t)(k0 + sr0) * ldq + sc0 * 8, Ks + s0 * 8);
        gld_lds16(Kbase + (size_t)(k0 + sr1) * ldq + sc1 * 8, Ks + s1 * 8);
        gld_lds16(Vbase + (size_t)sr0 * T + k0 + sc0 * 8, Vs + s0 * 8);
        gld_lds16(Vbase + (size_t)sr1 * T + k0 + sc1 * 8, Vs + s1 * 8);
        __syncthreads();  // drain DMA -> tiles ready

        // S = Q K^T  (B-frag: key n = jb*16+lm, k-chunk q / q+4)
        f32x4 s[4];
#pragma unroll
        for (int jb = 0; jb < 4; jb++) {
            int n = jb * 16 + lm;
            bf16x8 kf0 = *(const bf16x8*)&Ks[(n * 8 + (quad ^ lm7)) * 8];
            bf16x8 kf1 = *(const bf16x8*)&Ks[(n * 8 + ((quad + 4) ^ lm7)) * 8];
            f32x4 a = {0.f, 0.f, 0.f, 0.f};
            a = __builtin_amdgcn_mfma_f32_16x16x32_bf16(qf0, kf0, a, 0, 0, 0);
            a = __builtin_amdgcn_mfma_f32_16x16x32_bf16(qf1, kf1, a, 0, 0, 0);
            s[jb] = a;
        }
        // causal mask (diagonal tile only)
        if (kt == qt) {
#pragma unroll
            for (int jb = 0; jb < 4; jb++)
#pragma unroll
                for (int r = 0; r < 4; r++)
                    if (k0 + jb * 16 + lm > qrow0 + quad * 4 + r) s[jb][r] = -3.0e38f;
        }
        // online softmax
#pragma unroll
        for (int r = 0; r < 4; r++) {
            float mn = fmaxf(fmaxf(s[0][r], s[1][r]), fmaxf(s[2][r], s[3][r]));
            mn = fmaxf(mn, __shfl_xor(mn, 1));
            mn = fmaxf(mn, __shfl_xor(mn, 2));
            mn = fmaxf(mn, __shfl_xor(mn, 4));
            mn = fmaxf(mn, __shfl_xor(mn, 8));
            float mt = fmaxf(m_i[r], mn);
            float alpha = exp2f((m_i[r] - mt) * C);
            m_i[r] = mt;
            float nb = -mt * C;
            float rs = 0.f;
#pragma unroll
            for (int jb = 0; jb < 4; jb++) {
                float p = exp2f(fmaf(s[jb][r], C, nb));
                s[jb][r] = p;
                rs += p;
            }
            rs += __shfl_xor(rs, 1);
            rs += __shfl_xor(rs, 2);
            rs += __shfl_xor(rs, 4);
            rs += __shfl_xor(rs, 8);
            l_i[r] = l_i[r] * alpha + rs;
#pragma unroll
            for (int db = 0; db < 4; db++) o[db][r] *= alpha;
        }
        // P: C/D layout -> LDS (per-wave XOR swizzle)
#pragma unroll
        for (int jb = 0; jb < 4; jb++) {
            int g = jb * 2 + (lm >> 3);
#pragma unroll
            for (int r = 0; r < 4; r++) {
                int row = quad * 4 + r;
                PsW[row * 64 + ((g ^ (row & 7)) * 8) + lm7] = (bf16)s[jb][r];
            }
        }
        // O += P V  (B-frag: dim n = db*16+lm, token-chunk q / q+4)
        bf16x8 pf0 = *(const bf16x8*)&PsW[lm * 64 + ((quad ^ lm7) * 8)];
        bf16x8 pf1 = *(const bf16x8*)&PsW[lm * 64 + (((quad + 4) ^ lm7) * 8)];
#pragma unroll
        for (int db = 0; db < 4; db++) {
            int n = db * 16 + lm;
            bf16x8 vf0 = *(const bf16x8*)&Vs[(n * 8 + (quad ^ lm7)) * 8];
            bf16x8 vf1 = *(const bf16x8*)&Vs[(n * 8 + ((quad + 4) ^ lm7)) * 8];
            o[db] = __builtin_amdgcn_mfma_f32_16x16x32_bf16(pf0, vf0, o[db], 0, 0, 0);
            o[db] = __builtin_amdgcn_mfma_f32_16x16x32_bf16(pf1, vf1, o[db], 0, 0, 0);
        }
    }

    // epilogue: O / l -> bf16
    float inv[4];
#pragma unroll
    for (int r = 0; r < 4; r++) inv[r] = 1.f / l_i[r];
    bf16* Ob = Og + ((size_t)(b * T + qrow0 + quad * 4)) * D_MODEL + h * HEAD_SIZE + lm;
#pragma unroll
    for (int r = 0; r < 4; r++)
#pragma unroll
        for (int db = 0; db < 4; db++)
            Ob[(size_t)r * D_MODEL + db * 16] = (bf16)(o[db][r] * inv[r]);
}

extern "C" void kernel_launch(void* const* d_in, const int* in_sizes, int n_in,
                              void* d_out, int out_size, void* d_ws, size_t ws_size,
                              hipStream_t stream) {
    const float* x          = (const float*)d_in[0];
    const float* rms_scale  = (const float*)d_in[1];
    const float* in_proj_w  = (const float*)d_in[2];
    const float* in_proj_b  = (const float*)d_in[3];
    const float* out_proj_w = (const float*)d_in[4];
    const float* out_proj_b = (const float*)d_in[5];
    const float* w1         = (const float*)d_in[6];
    const float* b1         = (const float*)d_in[7];
    const float* w2         = (const float*)d_in[8];
    const float* b2         = (const float*)d_in[9];
    float* out = (float*)d_out;

    const int rows = in_sizes[0] / D_MODEL;  // 4096
    const int T = SEQ_T;
    const int B = rows / T;
    const int D = D_MODEL;

    bf16* inwb  = (bf16*)d_ws;                       // 3M
    bf16* outwb = inwb + (size_t)3 * D * D;          // 1M
    bf16* w1b   = outwb + (size_t)D * D;             // 4M
    bf16* w2b   = w1b + (size_t)4 * D * D;           // 4M
    bf16* XNb   = w2b + (size_t)4 * D * D;           // rows*D (reused as CTXb)
    bf16* RPb   = XNb + (size_t)rows * D;            // rows*D (reused as YNb)
    bf16* QKV   = RPb + (size_t)rows * D;            // rows*3D (H1b spans rows*4D)
    bf16* Vt    = QKV + (size_t)rows * 3 * D;        // rows*D  (tail of H1b region)
    bf16* CTXb  = XNb;
    bf16* YNb   = RPb;
    bf16* H1b   = QKV;

    // 0. cast all weights to bf16 (one kernel)
    {
        int n0 = 3 * D * D, n1 = D * D, n2 = 4 * D * D, n3 = 4 * D * D;
        int tot4 = (n0 + n1 + n2 + n3) / 4;
        cast_all_weights<<<(tot4 + 255) / 256, 256, 0, stream>>>(
            in_proj_w, inwb, n0, out_proj_w, outwb, n1, w1, w1b, n2, w2, w2b, n3);
    }
    // 1+2. fused rmsnorm + rope
    rmsnorm_rope_kernel<<<rows, 256, 0, stream>>>(x, rms_scale, XNb, RPb, T);
    // 3. fused QKV projection; Q/K -> QKV buffer, V -> Vt (transposed)
    {
        dim3 g(3 * D / 128, rows / 128);
        gemm_bf16<0, 0, 1, 1><<<g, 256, 0, stream>>>(RPb, XNb, 2 * D, inwb, in_proj_b,
                                                     nullptr, QKV, Vt, T, rows, 3 * D, D);
    }
    // 4. attention -> CTXb (bf16): 1024 balanced 4-wave blocks, LDS-staged K/V
    attn_mfma_kernel<<<B * NUM_HEADS * (T / 64), 256, 0, stream>>>(QKV, Vt, CTXb, T);
    // 5. y = CTXb @ out_proj^T + b -> d_out (fp32), skinny tiles (512 blocks)
    {
        dim3 g(D / 128, rows / 64);
        gemm_bf16_skinny<0><<<g, 256, 0, stream>>>(CTXb, outwb, out_proj_b, out,
                                                   rows, D, D);
    }
    // 6. yn = rmsnorm(y) -> bf16
    rmsnorm_kernel<<<rows, 256, 0, stream>>>(out, rms_scale, YNb);
    // 7. H1b = silu(yn @ w1^T + b1) (bf16)
    {
        dim3 g(4 * D / 128, rows / 128);
        gemm_bf16<1, 0, 1, 0><<<g, 256, 0, stream>>>(YNb, YNb, 4 * D, w1b, b1,
                                                     nullptr, H1b, nullptr, 1, rows, 4 * D, D);
    }
    // 8. out += H1b @ w2^T + b2 (fp32 residual), skinny tiles (512 blocks)
    {
        dim3 g(D / 128, rows / 64);
        gemm_bf16_skinny<1><<<g, 256, 0, stream>>>(H1b, w2b, b2, out,
                                                   rows, D, 4 * D);
    }
}

// Round 11
// 412.873 us; speedup vs baseline: 1.8636x; 1.0271x over previous
//
#include <hip/hip_runtime.h>
#include <math.h>
#include <stdint.h>

#define D_MODEL 1024
#define NUM_HEADS 16
#define HEAD_SIZE 64
#define SEQ_T 2048

typedef __bf16 bf16;
typedef __bf16 bf16x8 __attribute__((ext_vector_type(8)));
typedef float f32x4 __attribute__((ext_vector_type(4)));

__device__ __forceinline__ void gld_lds16(const bf16* g, bf16* l) {
    __builtin_amdgcn_global_load_lds(
        (__attribute__((address_space(1))) void*)(const_cast<bf16*>(g)),
        (__attribute__((address_space(3))) void*)(l), 16, 0, 0);
}

struct __align__(8) b4pack { bf16 v[4]; };

// ---------------- fused f32 -> bf16 cast of all 4 weight matrices ----------------
__global__ __launch_bounds__(256) void cast_all_weights(const float* __restrict__ s0, bf16* __restrict__ d0, int n0,
                                                        const float* __restrict__ s1, bf16* __restrict__ d1, int n1,
                                                        const float* __restrict__ s2, bf16* __restrict__ d2, int n2,
                                                        const float* __restrict__ s3, bf16* __restrict__ d3, int n3) {
    int i = (blockIdx.x * 256 + threadIdx.x) * 4;
    const float* src;
    bf16* dst;
    if (i < n0) { src = s0; dst = d0; }
    else if (i < n0 + n1) { i -= n0; src = s1; dst = d1; }
    else if (i < n0 + n1 + n2) { i -= n0 + n1; src = s2; dst = d2; }
    else { i -= n0 + n1 + n2; if (i >= n3) return; src = s3; dst = d3; }
    float4 v = *(const float4*)(src + i);
    b4pack o;
    o.v[0] = (bf16)v.x; o.v[1] = (bf16)v.y; o.v[2] = (bf16)v.z; o.v[3] = (bf16)v.w;
    *(b4pack*)(dst + i) = o;
}

// ---------------- fused RMSNorm + RoPE ----------------
__global__ __launch_bounds__(256) void rmsnorm_rope_kernel(const float* __restrict__ x,
                                                           const float* __restrict__ scale,
                                                           bf16* __restrict__ xn,
                                                           bf16* __restrict__ rp, int T) {
    __shared__ float red[4];
    int row = blockIdx.x;
    int t = row % T;
    const float* xp = x + (size_t)row * D_MODEL;
    int tid = threadIdx.x;
    float4 xv = *(const float4*)(xp + tid * 4);
    float s = xv.x * xv.x + xv.y * xv.y + xv.z * xv.z + xv.w * xv.w;
    for (int off = 32; off; off >>= 1) s += __shfl_down(s, off);
    if ((tid & 63) == 0) red[tid >> 6] = s;
    __syncthreads();
    if (tid == 0) red[0] = red[0] + red[1] + red[2] + red[3];
    __syncthreads();
    float inv = rsqrtf(red[0] * (1.0f / D_MODEL) + 1e-6f);
    float4 sc = *(const float4*)(scale + tid * 4);
    float n0 = xv.x * inv * sc.x, n1 = xv.y * inv * sc.y;
    float n2 = xv.z * inv * sc.z, n3 = xv.w * inv * sc.w;
    b4pack pn;
    pn.v[0] = (bf16)n0; pn.v[1] = (bf16)n1; pn.v[2] = (bf16)n2; pn.v[3] = (bf16)n3;
    *(b4pack*)(xn + (size_t)row * D_MODEL + tid * 4) = pn;
    int p0 = 2 * tid;
    float th0 = expf(-0.2878231366242557f * (float)(p0 & 31));        // ln(10000)/32
    float th1 = expf(-0.2878231366242557f * (float)((p0 + 1) & 31));
    float s0, c0, s1, c1;
    sincosf((float)t * th0, &s0, &c0);
    sincosf((float)t * th1, &s1, &c1);
    b4pack pr;
    pr.v[0] = (bf16)(n0 * c0 - n1 * s0);
    pr.v[1] = (bf16)(n1 * c0 + n0 * s0);
    pr.v[2] = (bf16)(n2 * c1 - n3 * s1);
    pr.v[3] = (bf16)(n3 * c1 + n2 * s1);
    *(b4pack*)(rp + (size_t)row * D_MODEL + tid * 4) = pr;
}

// ---------------- RMSNorm only ----------------
__global__ __launch_bounds__(256) void rmsnorm_kernel(const float* __restrict__ x,
                                                      const float* __restrict__ scale,
                                                      bf16* __restrict__ out) {
    __shared__ float red[4];
    int row = blockIdx.x;
    const float* xp = x + (size_t)row * D_MODEL;
    bf16* op = out + (size_t)row * D_MODEL;
    int tid = threadIdx.x;
    float s = 0.f;
    for (int i = tid; i < D_MODEL; i += 256) { float v = xp[i]; s += v * v; }
    for (int off = 32; off; off >>= 1) s += __shfl_down(s, off);
    if ((tid & 63) == 0) red[tid >> 6] = s;
    __syncthreads();
    if (tid == 0) red[0] = red[0] + red[1] + red[2] + red[3];
    __syncthreads();
    float inv = rsqrtf(red[0] * (1.0f / D_MODEL) + 1e-6f);
    for (int i = tid; i < D_MODEL; i += 256) op[i] = (bf16)(xp[i] * inv * scale[i]);
}

// ---------------- bf16 MFMA GEMM, 128x128 tile (m97 structure) ----------------
template <int ACT, int ADD, int OUT_BF16, int VT>
__global__ __launch_bounds__(256) void gemm_bf16(const bf16* __restrict__ A,
                                                 const bf16* __restrict__ A2, int splitN,
                                                 const bf16* __restrict__ W,
                                                 const float* __restrict__ bias,
                                                 float* __restrict__ Cf,
                                                 bf16* __restrict__ Cb,
                                                 bf16* __restrict__ Vtp, int Tlen,
                                                 int M, int N, int K) {
    __shared__ __align__(16) bf16 As[128 * 32];
    __shared__ __align__(16) bf16 Bs[128 * 32];
    int tid = threadIdx.x;
    int m0 = blockIdx.y * 128, n0 = blockIdx.x * 128;
    const bf16* Ag = (n0 < splitN) ? A : A2;

    int lane = tid & 63, w = tid >> 6;
    int wm = w >> 1, wn = w & 1;
    int lm = lane & 15, quad = lane >> 4;

    int c0 = tid, c1 = tid + 256;
    int ar0 = c0 >> 2, ak0 = (c0 & 3) * 8;
    int ar1 = c1 >> 2, ak1 = (c1 & 3) * 8;

    f32x4 acc[4][4];
#pragma unroll
    for (int i = 0; i < 4; i++)
#pragma unroll
        for (int j = 0; j < 4; j++)
#pragma unroll
            for (int r = 0; r < 4; r++) acc[i][j][r] = 0.f;

    int abase = (wm * 64 + lm) * 32 + quad * 8;
    int bbase = (wn * 64 + lm) * 32 + quad * 8;

    for (int k0 = 0; k0 < K; k0 += 32) {
        __syncthreads();
        gld_lds16(Ag + (size_t)(m0 + ar0) * K + k0 + ak0, As + c0 * 8);
        gld_lds16(Ag + (size_t)(m0 + ar1) * K + k0 + ak1, As + c1 * 8);
        gld_lds16(W  + (size_t)(n0 + ar0) * K + k0 + ak0, Bs + c0 * 8);
        gld_lds16(W  + (size_t)(n0 + ar1) * K + k0 + ak1, Bs + c1 * 8);
        __syncthreads();
        bf16x8 af[4], bfr[4];
#pragma unroll
        for (int i = 0; i < 4; i++) af[i] = *(const bf16x8*)&As[abase + i * 16 * 32];
#pragma unroll
        for (int j = 0; j < 4; j++) bfr[j] = *(const bf16x8*)&Bs[bbase + j * 16 * 32];
#pragma unroll
        for (int i = 0; i < 4; i++)
#pragma unroll
            for (int j = 0; j < 4; j++)
                acc[i][j] = __builtin_amdgcn_mfma_f32_16x16x32_bf16(af[i], bfr[j], acc[i][j], 0, 0, 0);
    }

    if (VT && n0 >= 2 * D_MODEL) {
#pragma unroll
        for (int j = 0; j < 4; j++) {
            int col = n0 + wn * 64 + j * 16 + lm;
            int dimg = col - 2 * D_MODEL;
            float bv = bias[col];
#pragma unroll
            for (int i = 0; i < 4; i++) {
                int row0 = m0 + wm * 64 + i * 16 + quad * 4;
                int bb = row0 / Tlen, t0 = row0 % Tlen;
                b4pack pk;
#pragma unroll
                for (int r = 0; r < 4; r++) pk.v[r] = (bf16)(acc[i][j][r] + bv);
                *(b4pack*)(Vtp + ((size_t)bb * D_MODEL + dimg) * Tlen + t0) = pk;
            }
        }
        return;
    }

#pragma unroll
    for (int j = 0; j < 4; j++) {
        int col = n0 + wn * 64 + j * 16 + lm;
        float bv = bias[col];
#pragma unroll
        for (int i = 0; i < 4; i++) {
#pragma unroll
            for (int r = 0; r < 4; r++) {
                int row = m0 + wm * 64 + i * 16 + quad * 4 + r;
                float v = acc[i][j][r] + bv;
                if (ACT == 1) v = v / (1.f + __expf(-v));
                size_t idx = (size_t)row * N + col;
                if (ADD) v += Cf[idx];
                if (OUT_BF16) Cb[idx] = (bf16)v;
                else Cf[idx] = v;
            }
        }
    }
}

// ---------------- skinny bf16 MFMA GEMM, 64x128 tile (for N=1024 GEMMs) -------------
template <int ADD>
__global__ __launch_bounds__(256) void gemm_bf16_skinny(const bf16* __restrict__ A,
                                                        const bf16* __restrict__ W,
                                                        const float* __restrict__ bias,
                                                        float* __restrict__ Cf,
                                                        int M, int N, int K) {
    __shared__ __align__(16) bf16 As[64 * 32];   // 4 KB
    __shared__ __align__(16) bf16 Bs[128 * 32];  // 8 KB
    int tid = threadIdx.x;
    int m0 = blockIdx.y * 64, n0 = blockIdx.x * 128;

    int lane = tid & 63, w = tid >> 6;
    int lm = lane & 15, quad = lane >> 4;

    int ar = tid >> 2, ak = (tid & 3) * 8;         // A: 256 chunks
    int c1 = tid + 256;
    int br1 = c1 >> 2, bk1 = (c1 & 3) * 8;         // B: 512 chunks

    f32x4 acc[8];
#pragma unroll
    for (int j = 0; j < 8; j++)
#pragma unroll
        for (int r = 0; r < 4; r++) acc[j][r] = 0.f;

    int abase = (w * 16 + lm) * 32 + quad * 8;
    int bbase = lm * 32 + quad * 8;

    for (int k0 = 0; k0 < K; k0 += 32) {
        __syncthreads();
        gld_lds16(A + (size_t)(m0 + ar) * K + k0 + ak, As + tid * 8);
        gld_lds16(W + (size_t)(n0 + ar) * K + k0 + ak, Bs + tid * 8);
        gld_lds16(W + (size_t)(n0 + br1) * K + k0 + bk1, Bs + c1 * 8);
        __syncthreads();
        bf16x8 af = *(const bf16x8*)&As[abase];
#pragma unroll
        for (int j = 0; j < 8; j++) {
            bf16x8 bfr = *(const bf16x8*)&Bs[bbase + j * 16 * 32];
            acc[j] = __builtin_amdgcn_mfma_f32_16x16x32_bf16(af, bfr, acc[j], 0, 0, 0);
        }
    }

#pragma unroll
    for (int j = 0; j < 8; j++) {
        int col = n0 + j * 16 + lm;
        float bv = bias[col];
#pragma unroll
        for (int r = 0; r < 4; r++) {
            int row = m0 + w * 16 + quad * 4 + r;
            float v = acc[j][r] + bv;
            size_t idx = (size_t)row * N + col;
            if (ADD) v += Cf[idx];
            Cf[idx] = v;
        }
    }
}

// ---------------- MFMA flash attention: 128-key rounds, LDS-staged K/V --------------
// Two 64-key K/V tiles staged per barrier pair; softmax runs ONCE per 128 keys
// (half the barriers, shuffle trees, alpha-exps and o-rescales of the 64-key
// version — R10 showed softmax/barrier overhead dominates: MfmaUtil 7% at 101 us).
// P round-trip stays per-wave (8 KB), reused for both PV sub-steps (same-wave
// ds ordering, no barrier). LDS 40 KB -> 4 blocks/CU. Work per block ~ (qt+2)>>1,
// sums to 34 for every CU-slot of the 4-round boustrophedon grid (balance kept).
__global__ __launch_bounds__(256) void attn_mfma_kernel(const bf16* __restrict__ QKV,
                                                        const bf16* __restrict__ Vt,
                                                        bf16* __restrict__ Og, int T) {
    __shared__ __align__(16) bf16 Ks0[64 * 64];     // 8 KB each
    __shared__ __align__(16) bf16 Ks1[64 * 64];
    __shared__ __align__(16) bf16 Vs0[64 * 64];
    __shared__ __align__(16) bf16 Vs1[64 * 64];
    __shared__ __align__(16) bf16 Ps[4 * 16 * 64];  // 8 KB, per-wave XOR-swizzled P
    const int ldq = 3 * D_MODEL;
    int bidx = blockIdx.x;
    int c = bidx & 7;
    int rest = bidx >> 3;           // [0,128)
    int r4 = rest >> 5;             // round 0..3
    int w5 = rest & 31;
    int bhoct = w5 >> 3;            // bh>>3
    int tslot = w5 & 7;
    int bh = bhoct * 8 + c;
    int qt = (r4 & 1) ? (24 - 8 * r4 + tslot) : (31 - 8 * r4 - tslot);
    int h = bh & (NUM_HEADS - 1), b = bh / NUM_HEADS;
    int tid = threadIdx.x;
    int w = tid >> 6, lane = tid & 63;
    int lm = lane & 15, quad = lane >> 4;
    int q0 = qt * 64, qrow0 = q0 + w * 16;

    // staging chunk ids: 512 x 16B chunks per 64x64 tile; source-swizzled
    int s0 = tid, s1 = tid + 256;
    int sr0 = s0 >> 3, sc0 = (s0 & 7) ^ (sr0 & 7);
    int sr1 = s1 >> 3, sc1 = (s1 & 7) ^ (sr1 & 7);

    const bf16* Qp = QKV + ((size_t)(b * T + qrow0 + lm)) * ldq + h * HEAD_SIZE + quad * 8;
    bf16x8 qf0 = *(const bf16x8*)Qp;
    bf16x8 qf1 = *(const bf16x8*)(Qp + 32);

    const bf16* Kbase = QKV + ((size_t)b * T) * ldq + D_MODEL + h * HEAD_SIZE;
    const bf16* Vbase = Vt + ((size_t)b * D_MODEL + h * HEAD_SIZE) * T;
    const float C = 0.1803368801111204f;  // 0.125 * log2(e)
    bf16* PsW = Ps + w * 16 * 64;
    int lm7 = lm & 7;

    f32x4 o[4];
    float m_i[4], l_i[4];
#pragma unroll
    for (int r = 0; r < 4; r++) {
        m_i[r] = -3.0e38f;
        l_i[r] = 0.f;
        o[r] = (f32x4){0.f, 0.f, 0.f, 0.f};
    }

    int nkt2 = (qt + 2) >> 1;  // 128-key rounds (last may be half-masked)
    for (int kt = 0; kt < nkt2; kt++) {
        int k0 = kt * 128;
        __syncthreads();  // prev-iter LDS reads complete
        gld_lds16(Kbase + (size_t)(k0 + sr0) * ldq + sc0 * 8, Ks0 + s0 * 8);
        gld_lds16(Kbase + (size_t)(k0 + sr1) * ldq + sc1 * 8, Ks0 + s1 * 8);
        gld_lds16(Kbase + (size_t)(k0 + 64 + sr0) * ldq + sc0 * 8, Ks1 + s0 * 8);
        gld_lds16(Kbase + (size_t)(k0 + 64 + sr1) * ldq + sc1 * 8, Ks1 + s1 * 8);
        gld_lds16(Vbase + (size_t)sr0 * T + k0 + sc0 * 8, Vs0 + s0 * 8);
        gld_lds16(Vbase + (size_t)sr1 * T + k0 + sc1 * 8, Vs0 + s1 * 8);
        gld_lds16(Vbase + (size_t)sr0 * T + k0 + 64 + sc0 * 8, Vs1 + s0 * 8);
        gld_lds16(Vbase + (size_t)sr1 * T + k0 + 64 + sc1 * 8, Vs1 + s1 * 8);
        __syncthreads();  // drain DMA -> tiles ready

        // S = Q K^T over both 64-key subtiles
        f32x4 sa[2][4];
#pragma unroll
        for (int u = 0; u < 2; u++) {
            const bf16* Ksu = u ? Ks1 : Ks0;
#pragma unroll
            for (int jb = 0; jb < 4; jb++) {
                int n = jb * 16 + lm;
                bf16x8 kf0 = *(const bf16x8*)&Ksu[(n * 8 + (quad ^ lm7)) * 8];
                bf16x8 kf1 = *(const bf16x8*)&Ksu[(n * 8 + ((quad + 4) ^ lm7)) * 8];
                f32x4 a = {0.f, 0.f, 0.f, 0.f};
                a = __builtin_amdgcn_mfma_f32_16x16x32_bf16(qf0, kf0, a, 0, 0, 0);
                a = __builtin_amdgcn_mfma_f32_16x16x32_bf16(qf1, kf1, a, 0, 0, 0);
                sa[u][jb] = a;
            }
        }
        // causal mask (last round only; subtile 1 may be fully masked for even qt)
        if (kt == nkt2 - 1) {
#pragma unroll
            for (int u = 0; u < 2; u++)
#pragma unroll
                for (int jb = 0; jb < 4; jb++)
#pragma unroll
                    for (int r = 0; r < 4; r++)
                        if (k0 + u * 64 + jb * 16 + lm > qrow0 + quad * 4 + r)
                            sa[u][jb][r] = -3.0e38f;
        }
        // online softmax over 128 keys
#pragma unroll
        for (int r = 0; r < 4; r++) {
            float mn = fmaxf(fmaxf(sa[0][0][r], sa[0][1][r]), fmaxf(sa[0][2][r], sa[0][3][r]));
            mn = fmaxf(mn, fmaxf(fmaxf(sa[1][0][r], sa[1][1][r]), fmaxf(sa[1][2][r], sa[1][3][r])));
            mn = fmaxf(mn, __shfl_xor(mn, 1));
            mn = fmaxf(mn, __shfl_xor(mn, 2));
            mn = fmaxf(mn, __shfl_xor(mn, 4));
            mn = fmaxf(mn, __shfl_xor(mn, 8));
            float mt = fmaxf(m_i[r], mn);
            float alpha = exp2f((m_i[r] - mt) * C);
            m_i[r] = mt;
            float nb = -mt * C;
            float rs = 0.f;
#pragma unroll
            for (int u = 0; u < 2; u++)
#pragma unroll
                for (int jb = 0; jb < 4; jb++) {
                    float p = exp2f(fmaf(sa[u][jb][r], C, nb));
                    sa[u][jb][r] = p;
                    rs += p;
                }
            rs += __shfl_xor(rs, 1);
            rs += __shfl_xor(rs, 2);
            rs += __shfl_xor(rs, 4);
            rs += __shfl_xor(rs, 8);
            l_i[r] = l_i[r] * alpha + rs;
#pragma unroll
            for (int db = 0; db < 4; db++) o[db][r] *= alpha;
        }
        // PV sub-steps: P write (C-layout -> XOR-swizzled LDS), read A-frags, MFMA
#pragma unroll
        for (int u = 0; u < 2; u++) {
            const bf16* Vsu = u ? Vs1 : Vs0;
#pragma unroll
            for (int jb = 0; jb < 4; jb++) {
                int g = jb * 2 + (lm >> 3);
#pragma unroll
                for (int r = 0; r < 4; r++) {
                    int row = quad * 4 + r;
                    PsW[row * 64 + ((g ^ (row & 7)) * 8) + lm7] = (bf16)sa[u][jb][r];
                }
            }
            bf16x8 pf0 = *(const bf16x8*)&PsW[lm * 64 + ((quad ^ lm7) * 8)];
            bf16x8 pf1 = *(const bf16x8*)&PsW[lm * 64 + (((quad + 4) ^ lm7) * 8)];
#pragma unroll
            for (int db = 0; db < 4; db++) {
                int n = db * 16 + lm;
                bf16x8 vf0 = *(const bf16x8*)&Vsu[(n * 8 + (quad ^ lm7)) * 8];
                bf16x8 vf1 = *(const bf16x8*)&Vsu[(n * 8 + ((quad + 4) ^ lm7)) * 8];
                o[db] = __builtin_amdgcn_mfma_f32_16x16x32_bf16(pf0, vf0, o[db], 0, 0, 0);
                o[db] = __builtin_amdgcn_mfma_f32_16x16x32_bf16(pf1, vf1, o[db], 0, 0, 0);
            }
        }
    }

    // epilogue: O / l -> bf16
    float inv[4];
#pragma unroll
    for (int r = 0; r < 4; r++) inv[r] = 1.f / l_i[r];
    bf16* Ob = Og + ((size_t)(b * T + qrow0 + quad * 4)) * D_MODEL + h * HEAD_SIZE + lm;
#pragma unroll
    for (int r = 0; r < 4; r++)
#pragma unroll
        for (int db = 0; db < 4; db++)
            Ob[(size_t)r * D_MODEL + db * 16] = (bf16)(o[db][r] * inv[r]);
}

extern "C" void kernel_launch(void* const* d_in, const int* in_sizes, int n_in,
                              void* d_out, int out_size, void* d_ws, size_t ws_size,
                              hipStream_t stream) {
    const float* x          = (const float*)d_in[0];
    const float* rms_scale  = (const float*)d_in[1];
    const float* in_proj_w  = (const float*)d_in[2];
    const float* in_proj_b  = (const float*)d_in[3];
    const float* out_proj_w = (const float*)d_in[4];
    const float* out_proj_b = (const float*)d_in[5];
    const float* w1         = (const float*)d_in[6];
    const float* b1         = (const float*)d_in[7];
    const float* w2         = (const float*)d_in[8];
    const float* b2         = (const float*)d_in[9];
    float* out = (float*)d_out;

    const int rows = in_sizes[0] / D_MODEL;  // 4096
    const int T = SEQ_T;
    const int B = rows / T;
    const int D = D_MODEL;

    bf16* inwb  = (bf16*)d_ws;                       // 3M
    bf16* outwb = inwb + (size_t)3 * D * D;          // 1M
    bf16* w1b   = outwb + (size_t)D * D;             // 4M
    bf16* w2b   = w1b + (size_t)4 * D * D;           // 4M
    bf16* XNb   = w2b + (size_t)4 * D * D;           // rows*D (reused as CTXb)
    bf16* RPb   = XNb + (size_t)rows * D;            // rows*D (reused as YNb)
    bf16* QKV   = RPb + (size_t)rows * D;            // rows*3D (H1b spans rows*4D)
    bf16* Vt    = QKV + (size_t)rows * 3 * D;        // rows*D  (tail of H1b region)
    bf16* CTXb  = XNb;
    bf16* YNb   = RPb;
    bf16* H1b   = QKV;

    // 0. cast all weights to bf16 (one kernel)
    {
        int n0 = 3 * D * D, n1 = D * D, n2 = 4 * D * D, n3 = 4 * D * D;
        int tot4 = (n0 + n1 + n2 + n3) / 4;
        cast_all_weights<<<(tot4 + 255) / 256, 256, 0, stream>>>(
            in_proj_w, inwb, n0, out_proj_w, outwb, n1, w1, w1b, n2, w2, w2b, n3);
    }
    // 1+2. fused rmsnorm + rope
    rmsnorm_rope_kernel<<<rows, 256, 0, stream>>>(x, rms_scale, XNb, RPb, T);
    // 3. fused QKV projection; Q/K -> QKV buffer, V -> Vt (transposed)
    {
        dim3 g(3 * D / 128, rows / 128);
        gemm_bf16<0, 0, 1, 1><<<g, 256, 0, stream>>>(RPb, XNb, 2 * D, inwb, in_proj_b,
                                                     nullptr, QKV, Vt, T, rows, 3 * D, D);
    }
    // 4. attention -> CTXb (bf16): 1024 balanced 4-wave blocks, 128-key rounds
    attn_mfma_kernel<<<B * NUM_HEADS * (T / 64), 256, 0, stream>>>(QKV, Vt, CTXb, T);
    // 5. y = CTXb @ out_proj^T + b -> d_out (fp32), skinny tiles (512 blocks)
    {
        dim3 g(D / 128, rows / 64);
        gemm_bf16_skinny<0><<<g, 256, 0, stream>>>(CTXb, outwb, out_proj_b, out,
                                                   rows, D, D);
    }
    // 6. yn = rmsnorm(y) -> bf16
    rmsnorm_kernel<<<rows, 256, 0, stream>>>(out, rms_scale, YNb);
    // 7. H1b = silu(yn @ w1^T + b1) (bf16)
    {
        dim3 g(4 * D / 128, rows / 128);
        gemm_bf16<1, 0, 1, 0><<<g, 256, 0, stream>>>(YNb, YNb, 4 * D, w1b, b1,
                                                     nullptr, H1b, nullptr, 1, rows, 4 * D, D);
    }
    // 8. out += H1b @ w2^T + b2 (fp32 residual), skinny tiles (512 blocks)
    {
        dim3 g(D / 128, rows / 64);
        gemm_bf16_skinny<1><<<g, 256, 0, stream>>>(H1b, w2b, b2, out,
                                                   rows, D, 4 * D);
    }
}